// Round 4
// baseline (142.325 us; speedup 1.0000x reference)
//
#include <hip/hip_runtime.h>
#include <hip/hip_bf16.h>

#define HW    3136
#define C_IN  256
#define G_    16
#define GC_   16
#define IMGH  56
#define IMGW  56
#define EPSV  1e-5f

// xpad geometry: 62 rows (h -3..58), 64-word row stride
#define PROWS 62
#define PRSTR 64
#define KSTR  118   // s_kern words per ko: 2 rows x 58 + 2 pad

typedef __bf16 bf16x8 __attribute__((ext_vector_type(8)));
typedef float  f32x4  __attribute__((ext_vector_type(4)));

static __device__ __forceinline__ unsigned short f2bf(float f) {
    union { float f; unsigned u; } v; v.f = f;
    unsigned r = (v.u + 0x7FFFu + ((v.u >> 16) & 1u)) >> 16;   // RNE
    return (unsigned short)r;
}

// ---------------------------------------------------------------------------
// k_pad: xpad[bc][row 0..61][col 0..63] = x zero-padded by 3 (fp32).
// 992 blocks x 256 thr, 4 float4 per thread. 1024 bc x 992 float4 each.
// ---------------------------------------------------------------------------
__global__ __launch_bounds__(256) void k_pad(
    const float* __restrict__ x, float* __restrict__ xpad)
{
    int F0 = blockIdx.x * 1024 + threadIdx.x;
#pragma unroll
    for (int it = 0; it < 4; ++it) {
        int F   = F0 + it * 256;
        int bc  = F / 992;
        int rem = F - bc * 992;
        int row = rem >> 4, col4 = (rem & 15) << 2;
        int hr  = row - 3;
        const float* xs = x + (size_t)bc * HW + hr * IMGW;
        float4 v;
        float* vp = (float*)&v;
#pragma unroll
        for (int j = 0; j < 4; ++j) {
            int wc = col4 + j - 3;
            vp[j] = (hr >= 0 && hr < IMGH && wc >= 0 && wc < IMGW) ? xs[wc] : 0.f;
        }
        *(float4*)(xpad + (size_t)bc * (PROWS * PRSTR) + row * PRSTR + col4) = v;
    }
}

// ---------------------------------------------------------------------------
// k_wcvt: Wbf = bf16(W_reduce) [64x256], Wsbf = bf16(W_span) [784x64].
// 65 blocks x 256 thr x 4 elems = 66560 = 16384 + 50176 exactly.
// ---------------------------------------------------------------------------
__global__ __launch_bounds__(256) void k_wcvt(
    const float* __restrict__ Wr, const float* __restrict__ Wspan,
    unsigned short* __restrict__ Wbf, unsigned short* __restrict__ Wsbf)
{
    int i4 = (blockIdx.x * 256 + threadIdx.x) * 4;
    if (i4 < 16384) {
#pragma unroll
        for (int j = 0; j < 4; ++j) Wbf[i4 + j] = f2bf(Wr[i4 + j]);
    } else {
        int j0 = i4 - 16384;
#pragma unroll
        for (int j = 0; j < 4; ++j) Wsbf[j0 + j] = f2bf(Wspan[j0 + j]);
    }
}

// ---------------------------------------------------------------------------
// k_reduce: xrT[pix][o] = bf16(relu(BN(W_reduce @ x + b)))  via MFMA.
// 784 blocks x 256 thr; wave = 16 pixels x 16 outs (mt = wave id).
// 3136 waves = 12/CU. B-frags: 8 strided fp32 loads; A-frags: b128 from Wbf.
// ---------------------------------------------------------------------------
__global__ __launch_bounds__(256) void k_reduce(
    const float* __restrict__ x,  const unsigned short* __restrict__ Wbf,
    const float* __restrict__ br, const float* __restrict__ gamma,
    const float* __restrict__ beta, const float* __restrict__ mean,
    const float* __restrict__ var, unsigned short* __restrict__ xrT)
{
    int t = threadIdx.x, wv = t >> 6, lane = t & 63;
    int ln = lane & 15, quad = lane >> 4;
    int p = blockIdx.x * 16 + ln;              // 16 | 3136 -> no batch straddle
    int b = blockIdx.x / 196;
    int l = p - b * HW;
    const float* xb = x + (size_t)b * C_IN * HW + l;

    f32x4 acc = (f32x4){0.f, 0.f, 0.f, 0.f};
#pragma unroll
    for (int ks = 0; ks < 8; ++ks) {
        int c0 = ks * 32 + quad * 8;
        float xv[8];
#pragma unroll
        for (int j = 0; j < 8; ++j) xv[j] = xb[(size_t)(c0 + j) * HW];
        union { unsigned short s[8]; bf16x8 v; } bfx;
#pragma unroll
        for (int j = 0; j < 8; ++j) bfx.s[j] = f2bf(xv[j]);
        bf16x8 af = *(const bf16x8*)(Wbf + (size_t)(wv * 16 + ln) * C_IN + c0);
        acc = __builtin_amdgcn_mfma_f32_16x16x32_bf16(af, bfx.v, acc, 0, 0, 0);
    }
    // D: col(pixel)=ln, row(out)=quad*4+r
    union { unsigned short s[4]; uint2 v; } pk;
#pragma unroll
    for (int r = 0; r < 4; ++r) {
        int o = wv * 16 + quad * 4 + r;
        float s  = gamma[o] * rsqrtf(var[o] + EPSV);
        float vv = (acc[r] + br[o] - mean[o]) * s + beta[o];
        pk.s[r] = f2bf(fmaxf(vv, 0.f));
    }
    *(uint2*)(xrT + (size_t)p * 64 + wv * 16 + quad * 4) = pk.v;
}

// ---------------------------------------------------------------------------
// k_invol: block = (b, g, row-pair). 512 thr. LDS = s_kern only (23.1 KB ->
// 4 blocks/CU, 32 waves). Phase A: MFMA kern from global bf16 frags.
// Phase B: 448 thr = 2 rows x 28 w-pairs x 8 c-pairs; kern via b64 LDS
// (broadcast across c), x via b64 global from xpad (L1-hot, imm offsets).
// ---------------------------------------------------------------------------
__global__ __launch_bounds__(512) void k_invol(
    const float* __restrict__ xpad, const unsigned short* __restrict__ xrT,
    const unsigned short* __restrict__ Wsbf, const float* __restrict__ bspan,
    float* __restrict__ out)
{
    __shared__ float s_kern[49 * KSTR];        // 23128 B

    int t = threadIdx.x;
    int bid = blockIdx.x;
    int xcd = bid & 7, jj = bid >> 3;          // XCD-stripe swizzle
    int g = jj & 15, rpb = jj >> 4;            // rpb in [0,14)
    int idx = xcd * 14 + rpb;                  // [0,112) = 4 b x 28 row-pairs
    int b = idx / 28, rp = idx - b * 28;
    int h0 = rp * 2;

    // ---- Phase A: kern[49][2x56] = Wspan_g @ xr + bias (MFMA) ----
    {
        int wv = t >> 6, lane = t & 63;
        int ln = lane & 15, quad = lane >> 4;
        int mt = wv & 3, nh = wv >> 2;
        int m0 = mt * 16;
        int ko_a = m0 + ln; if (ko_a > 48) ko_a = 48;
        const unsigned short* wrow = Wsbf + (size_t)(g * 49 + ko_a) * 64;
        int pixbase = b * HW + h0 * IMGW;      // 112 contiguous pixels

        f32x4 acc[4];
#pragma unroll
        for (int nt = 0; nt < 4; ++nt) acc[nt] = (f32x4){0.f, 0.f, 0.f, 0.f};

#pragma unroll
        for (int ks = 0; ks < 2; ++ks) {
            int c0 = ks * 32 + quad * 8;
            bf16x8 af = *(const bf16x8*)(wrow + c0);
#pragma unroll
            for (int nt = 0; nt < 4; ++nt) {
                int pp = nh * 64 + nt * 16 + ln;
                if (pp > 111) pp = 111;
                bf16x8 bb = *(const bf16x8*)(xrT + (size_t)(pixbase + pp) * 64 + c0);
                acc[nt] = __builtin_amdgcn_mfma_f32_16x16x32_bf16(af, bb, acc[nt], 0, 0, 0);
            }
        }
#pragma unroll
        for (int r = 0; r < 4; ++r) {
            int ko = m0 + quad * 4 + r;
            float bias = bspan[g * 49 + (ko < 49 ? ko : 48)];
#pragma unroll
            for (int nt = 0; nt < 4; ++nt) {
                int pp = nh * 64 + nt * 16 + ln;
                if (ko < 49 && pp < 112) {
                    int prow = pp / 56, pw = pp - prow * 56;
                    s_kern[ko * KSTR + prow * 58 + pw] = acc[nt][r] + bias;
                }
            }
        }
    }
    __syncthreads();

    // ---- Phase B ----
    if (t < 448) {
        int row = t / 224, rem = t - row * 224;
        int cp = rem / 28, wp = rem - cp * 28;
        int w0 = wp * 2;
        int c0 = cp * 2;

        const float* xr0 = xpad + ((size_t)(b * C_IN + g * GC_ + c0) * PROWS
                                   + (h0 + row)) * PRSTR + w0;
        const float* xr1 = xr0 + PROWS * PRSTR;
        const float* skb = s_kern + row * 58 + w0;

        float a00 = 0.f, a01 = 0.f, a10 = 0.f, a11 = 0.f;
#pragma unroll
        for (int r = 0; r < 7; ++r) {
            float2 kv[7];
#pragma unroll
            for (int dw = 0; dw < 7; ++dw)
                kv[dw] = *(const float2*)(skb + (r * 7 + dw) * KSTR);
            float xa[8], xc[8];
#pragma unroll
            for (int j = 0; j < 4; ++j) {
                float2 u = *(const float2*)(xr0 + r * PRSTR + 2 * j);
                xa[2 * j] = u.x; xa[2 * j + 1] = u.y;
                float2 w = *(const float2*)(xr1 + r * PRSTR + 2 * j);
                xc[2 * j] = w.x; xc[2 * j + 1] = w.y;
            }
#pragma unroll
            for (int dw = 0; dw < 7; ++dw) {
                a00 += kv[dw].x * xa[dw];
                a01 += kv[dw].y * xa[dw + 1];
                a10 += kv[dw].x * xc[dw];
                a11 += kv[dw].y * xc[dw + 1];
            }
        }
        float* ob = out + (size_t)(b * C_IN + g * GC_ + c0) * HW + (h0 + row) * IMGW + w0;
        *(float2*)ob = make_float2(a00, a01);
        *(float2*)(ob + HW) = make_float2(a10, a11);
    }
}

// ---------------------------------------------------------------------------
extern "C" void kernel_launch(void* const* d_in, const int* in_sizes, int n_in,
                              void* d_out, int out_size, void* d_ws, size_t ws_size,
                              hipStream_t stream)
{
    const float* x   = (const float*)d_in[0];
    const float* Wr  = (const float*)d_in[1];
    const float* br  = (const float*)d_in[2];
    const float* gm  = (const float*)d_in[3];
    const float* bt  = (const float*)d_in[4];
    const float* mn  = (const float*)d_in[5];
    const float* vr  = (const float*)d_in[6];
    const float* Ws  = (const float*)d_in[7];
    const float* bs  = (const float*)d_in[8];
    float* out = (float*)d_out;

    char* ws = (char*)d_ws;
    unsigned short* xrT  = (unsigned short*)ws;                    // 1,605,632 B
    float*          xpad = (float*)(ws + 1605632);                 // 16,252,928 B
    unsigned short* Wbf  = (unsigned short*)(ws + 17858560);       // 32,768 B
    unsigned short* Wsbf = (unsigned short*)(ws + 17891328);       // 100,352 B

    k_wcvt  <<<dim3(65),   256, 0, stream>>>(Wr, Ws, Wbf, Wsbf);
    k_pad   <<<dim3(992),  256, 0, stream>>>(x, xpad);
    k_reduce<<<dim3(784),  256, 0, stream>>>(x, Wbf, br, gm, bt, mn, vr, xrT);
    k_invol <<<dim3(1792), 512, 0, stream>>>(xpad, xrT, Wsbf, bs, out);
}

// Round 5
// 116.154 us; speedup vs baseline: 1.2253x; 1.2253x over previous
//
#include <hip/hip_runtime.h>
#include <hip/hip_bf16.h>

#define HW    3136
#define C_IN  256
#define G_    16
#define GC_   16
#define IMGH  56
#define IMGW  56
#define EPSV  1e-5f

#define PROWS 62          // padded rows (h-3 .. h+58)
#define XROW  64          // xpad row stride in bf16 (128 B)
#define SXCH  528         // s_x per-channel stride in shorts (8*64 + 16 pad)
#define SKROW 2940        // s_kern per-output-row plane: 49 * 60 floats

typedef __bf16 bf16x8 __attribute__((ext_vector_type(8)));
typedef float  f32x4  __attribute__((ext_vector_type(4)));

static __device__ __forceinline__ unsigned short f2bf(float f) {
    union { float f; unsigned u; } v; v.f = f;
    unsigned r = (v.u + 0x7FFFu + ((v.u >> 16) & 1u)) >> 16;   // RNE
    return (unsigned short)r;
}
static __device__ __forceinline__ float bf2f(unsigned short s) {
    union { unsigned u; float f; } v; v.u = (unsigned)s << 16;
    return v.f;
}

// ---------------------------------------------------------------------------
// k_prep: blocks 0..495  -> xpad bf16 [1024][62][64] zero-padded by 3
//         blocks 496..560 -> Wbf = bf16(W_reduce), Wsbf = bf16(W_span)
// ---------------------------------------------------------------------------
__global__ __launch_bounds__(256) void k_prep(
    const float* __restrict__ x, const float* __restrict__ Wr,
    const float* __restrict__ Wspan, unsigned short* __restrict__ xpad,
    unsigned short* __restrict__ Wbf, unsigned short* __restrict__ Wsbf)
{
    int blk = blockIdx.x, t = threadIdx.x;
    if (blk < 496) {
        int F0 = blk * 1024 + t;
#pragma unroll
        for (int it = 0; it < 4; ++it) {
            int F   = F0 + it * 256;              // < 507904 = 1024*496
            int bc  = F / 496;
            int rem = F - bc * 496;
            int row = rem >> 3, oct = rem & 7;
            int hr  = row - 3;
            const float* xs = x + (size_t)bc * HW + hr * IMGW;
            union { unsigned short s[8]; uint4 v; } pk;
#pragma unroll
            for (int j = 0; j < 8; ++j) {
                int wc = oct * 8 + j - 3;
                float vv = (hr >= 0 && hr < IMGH && wc >= 0 && wc < IMGW) ? xs[wc] : 0.f;
                pk.s[j] = f2bf(vv);
            }
            *(uint4*)(xpad + ((size_t)bc * PROWS + row) * XROW + oct * 8) = pk.v;
        }
    } else {
        int i4 = ((blk - 496) * 256 + t) * 4;     // 66560*4... covers 16384+50176
        if (i4 < 16384) {
#pragma unroll
            for (int j = 0; j < 4; ++j) Wbf[i4 + j] = f2bf(Wr[i4 + j]);
        } else {
            int j0 = i4 - 16384;
#pragma unroll
            for (int j = 0; j < 4; ++j) Wsbf[j0 + j] = f2bf(Wspan[j0 + j]);
        }
    }
}

// ---------------------------------------------------------------------------
// k_reduce: xrT[pix][o] = bf16(relu(BN(W_reduce@x + b))) via MFMA.
// 392 blocks x 128 thr; wave = 16 px x 64 outs (mt loop). x read once.
// ---------------------------------------------------------------------------
__global__ __launch_bounds__(128) void k_reduce(
    const float* __restrict__ x,  const unsigned short* __restrict__ Wbf,
    const float* __restrict__ br, const float* __restrict__ gamma,
    const float* __restrict__ beta, const float* __restrict__ mean,
    const float* __restrict__ var, unsigned short* __restrict__ xrT)
{
    int t = threadIdx.x, wv = t >> 6, lane = t & 63;
    int ln = lane & 15, quad = lane >> 4;
    int p = blockIdx.x * 32 + wv * 16 + ln;    // 32 | 3136 -> no batch straddle
    int b = blockIdx.x / 98;
    int l = p - b * HW;
    const float* xb = x + (size_t)b * C_IN * HW + l;

    f32x4 acc[4];
#pragma unroll
    for (int mt = 0; mt < 4; ++mt) acc[mt] = (f32x4){0.f, 0.f, 0.f, 0.f};

#pragma unroll
    for (int ks = 0; ks < 8; ++ks) {
        int c0 = ks * 32 + quad * 8;
        float xv[8];
#pragma unroll
        for (int j = 0; j < 8; ++j) xv[j] = xb[(size_t)(c0 + j) * HW];
        union { unsigned short s[8]; bf16x8 v; } bfx;
#pragma unroll
        for (int j = 0; j < 8; ++j) bfx.s[j] = f2bf(xv[j]);
#pragma unroll
        for (int mt = 0; mt < 4; ++mt) {
            bf16x8 af = *(const bf16x8*)(Wbf + (size_t)(mt * 16 + ln) * C_IN + c0);
            acc[mt] = __builtin_amdgcn_mfma_f32_16x16x32_bf16(af, bfx.v, acc[mt], 0, 0, 0);
        }
    }
#pragma unroll
    for (int mt = 0; mt < 4; ++mt) {
        union { unsigned short s[4]; uint2 v; } pk;
#pragma unroll
        for (int r = 0; r < 4; ++r) {
            int o = mt * 16 + quad * 4 + r;
            float s  = gamma[o] * rsqrtf(var[o] + EPSV);
            float vv = (acc[mt][r] + br[o] - mean[o]) * s + beta[o];
            pk.s[r] = f2bf(fmaxf(vv, 0.f));
        }
        *(uint2*)(xrT + (size_t)p * 64 + mt * 16 + quad * 4) = pk.v;
    }
}

// ---------------------------------------------------------------------------
// k_invol: block = (b, g, row-pair). 512 thr.
//  stage: 16 x 1KB global_load_lds chunks (xpad bf16 -> s_x, no VGPR trip)
//  Phase A: kern[2][49][56] = Wspan_g @ xr + bias (MFMA, frags from global)
//  Phase B: 224 thr = 2 rows x 14 w-quads x 8 c-pairs; kern b128 from LDS,
//           x b64 bf16 from LDS. All aligned.
// LDS 40.4 KB.
// ---------------------------------------------------------------------------
__global__ __launch_bounds__(512, 6) void k_invol(
    const unsigned short* __restrict__ xpad, const unsigned short* __restrict__ xrT,
    const unsigned short* __restrict__ Wsbf, const float* __restrict__ bspan,
    float* __restrict__ out)
{
    __shared__ __align__(16) unsigned short s_x[GC_ * SXCH];   // 16896 B
    __shared__ __align__(16) float s_kern[2 * SKROW];          // 23520 B

    int t = threadIdx.x;
    int bid = blockIdx.x;
    int xcd = bid & 7, jj = bid >> 3;          // XCD-stripe swizzle
    int g = jj & 15, rpb = jj >> 4;            // rpb in [0,14)
    int idx = xcd * 14 + rpb;                  // [0,112) = 4 b x 28 row-pairs
    int b = idx / 28, rp = idx - b * 28;
    int h0 = rp * 2;

    int wv = t >> 6, lane = t & 63;

    // ---- async stage x: wave wv loads channels 2wv, 2wv+1 (1 KB each) ----
#pragma unroll
    for (int i = 0; i < 2; ++i) {
        int c = wv * 2 + i;
        const unsigned short* gsrc = xpad
            + ((size_t)(b * C_IN + g * GC_ + c) * PROWS + h0) * XROW + lane * 8;
        __builtin_amdgcn_global_load_lds(
            (const __attribute__((address_space(1))) void*)gsrc,
            (__attribute__((address_space(3))) void*)&s_x[c * SXCH],
            16, 0, 0);
    }

    // ---- Phase A: kern = Wspan_g @ xr + bias (MFMA) ----
    {
        int ln = lane & 15, quad = lane >> 4;
        int mt = wv & 3, nh = wv >> 2;
        int m0 = mt * 16;
        int ko_a = m0 + ln; if (ko_a > 48) ko_a = 48;
        const unsigned short* wrow = Wsbf + (size_t)(g * 49 + ko_a) * 64;
        int pixbase = b * HW + h0 * IMGW;      // 112 contiguous pixels

        f32x4 acc[4];
#pragma unroll
        for (int nt = 0; nt < 4; ++nt) acc[nt] = (f32x4){0.f, 0.f, 0.f, 0.f};

#pragma unroll
        for (int ks = 0; ks < 2; ++ks) {
            int c0 = ks * 32 + quad * 8;
            bf16x8 af = *(const bf16x8*)(wrow + c0);
#pragma unroll
            for (int nt = 0; nt < 4; ++nt) {
                int pp = nh * 64 + nt * 16 + ln;
                if (pp > 111) pp = 111;
                bf16x8 bb = *(const bf16x8*)(xrT + (size_t)(pixbase + pp) * 64 + c0);
                acc[nt] = __builtin_amdgcn_mfma_f32_16x16x32_bf16(af, bb, acc[nt], 0, 0, 0);
            }
        }
#pragma unroll
        for (int r = 0; r < 4; ++r) {
            int ko = m0 + quad * 4 + r;
            float bias = bspan[g * 49 + (ko < 49 ? ko : 48)];
#pragma unroll
            for (int nt = 0; nt < 4; ++nt) {
                int pp = nh * 64 + nt * 16 + ln;
                if (ko < 49 && pp < 112) {
                    int prow = pp / 56, pw = pp - prow * 56;
                    s_kern[prow * SKROW + ko * 60 + pw] = acc[nt][r] + bias;
                }
            }
        }
    }
    __syncthreads();

    // ---- Phase B: 224 thr, each 4 w x 2 c ----
    if (t < 224) {
        int wp  = t % 14;
        int row = (t / 14) & 1;
        int cp  = t / 28;                       // 0..7
        int w0  = wp * 4, c0 = cp * 2;

        const float* sk = s_kern + row * SKROW + w0;
        float a0[4], a1[4];
#pragma unroll
        for (int j = 0; j < 4; ++j) { a0[j] = 0.f; a1[j] = 0.f; }

#pragma unroll
        for (int r = 0; r < 7; ++r) {
            float4 kv[7];
#pragma unroll
            for (int dw = 0; dw < 7; ++dw)
                kv[dw] = *(const float4*)(sk + (r * 7 + dw) * 60);
#pragma unroll
            for (int ci = 0; ci < 2; ++ci) {
                const unsigned short* sx = s_x + (c0 + ci) * SXCH + (row + r) * XROW + w0;
                union { unsigned short s[12]; uint2 v[3]; } xr_;
                xr_.v[0] = *(const uint2*)(sx);
                xr_.v[1] = *(const uint2*)(sx + 4);
                xr_.v[2] = *(const uint2*)(sx + 8);
                float xf[10];
#pragma unroll
                for (int j = 0; j < 10; ++j) xf[j] = bf2f(xr_.s[j]);
                float* aa = ci ? a1 : a0;
#pragma unroll
                for (int dw = 0; dw < 7; ++dw) {
                    aa[0] += kv[dw].x * xf[dw];
                    aa[1] += kv[dw].y * xf[dw + 1];
                    aa[2] += kv[dw].z * xf[dw + 2];
                    aa[3] += kv[dw].w * xf[dw + 3];
                }
            }
        }
        float* ob = out + (size_t)(b * C_IN + g * GC_ + c0) * HW + (h0 + row) * IMGW + w0;
        *(float4*)ob = make_float4(a0[0], a0[1], a0[2], a0[3]);
        *(float4*)(ob + HW) = make_float4(a1[0], a1[1], a1[2], a1[3]);
    }
}

// ---------------------------------------------------------------------------
extern "C" void kernel_launch(void* const* d_in, const int* in_sizes, int n_in,
                              void* d_out, int out_size, void* d_ws, size_t ws_size,
                              hipStream_t stream)
{
    const float* x   = (const float*)d_in[0];
    const float* Wr  = (const float*)d_in[1];
    const float* br  = (const float*)d_in[2];
    const float* gm  = (const float*)d_in[3];
    const float* bt  = (const float*)d_in[4];
    const float* mn  = (const float*)d_in[5];
    const float* vr  = (const float*)d_in[6];
    const float* Ws  = (const float*)d_in[7];
    const float* bs  = (const float*)d_in[8];
    float* out = (float*)d_out;

    char* ws = (char*)d_ws;
    unsigned short* xrT  = (unsigned short*)ws;                 // 1,605,632 B
    unsigned short* xpad = (unsigned short*)(ws + 1605632);     // 8,126,464 B
    unsigned short* Wbf  = (unsigned short*)(ws + 9732096);     //    32,768 B
    unsigned short* Wsbf = (unsigned short*)(ws + 9764864);     //   100,352 B

    k_prep  <<<dim3(561),  256, 0, stream>>>(x, Wr, Ws, xpad, Wbf, Wsbf);
    k_reduce<<<dim3(392),  128, 0, stream>>>(x, Wbf, br, gm, bt, mn, vr, xrT);
    k_invol <<<dim3(1792), 512, 0, stream>>>(xpad, xrT, Wsbf, bs, out);
}